// Round 1
// baseline (920.800 us; speedup 1.0000x reference)
//
#include <hip/hip_runtime.h>
#include <hip/hip_cooperative_groups.h>
#include <cmath>

namespace cg = cooperative_groups;

#define Nn 96
#define INF 64
#define HIDF 256
#define ZD 64
#define TRIN 4656
#define NE 2048
#define NITER 50

// workspace layout (floats)
enum {
  OFF_AGG  = 0,                   // 96*96 dense normalized adjacency (built from edges)
  OFF_DEG  = OFF_AGG + Nn * Nn,   // 96
  OFF_DEGA = OFF_DEG + Nn,        // 96
  OFF_XW   = OFF_DEGA + Nn,       // 96*256  (x@W scratch, reused both layers)
  OFF_G    = OFF_XW + Nn * HIDF,  // 96*256  (AGG@XW + b)
  OFF_H1   = OFF_G + Nn * HIDF,   // 96*256
  OFF_POOL = OFF_H1 + Nn * HIDF,  // 256
  OFF_MU   = OFF_POOL + HIDF,     // 64
  OFF_LV   = OFF_MU + ZD,         // 64
  OFF_D1   = OFF_LV + ZD,         // 256
  OFF_KL   = OFF_D1 + HIDF,       // 1
  OFF_VEC  = OFF_KL + 1,          // 4656
  OFF_B    = OFF_VEC + TRIN,      // 96*96
  OFF_BD   = OFF_B + Nn * Nn,     // 96
  OFF_DEGB = OFF_BD + Nn,         // 96
  OFF_Q    = OFF_DEGB + Nn,       // 96*96 (row-major [a][b])
  OFF_DT   = OFF_Q + Nn * Nn,     // 96*96 (D transposed: [a][i])
  OFF_U0   = OFF_DT + Nn * Nn,    // 96*96 (x stored column-major of X: [a][i])
  OFF_U1   = OFF_U0 + Nn * Nn,    // 96*96
  OFF_P0   = OFF_U1 + Nn * Nn,    // 96 norm partials
  OFF_P1   = OFF_P0 + Nn,         // 96
  OFF_REC  = OFF_P1 + Nn,         // 1
  WS_END   = OFF_REC + 1
};

__device__ __forceinline__ int tri_idx(int i, int j) {  // i <= j
  return i * Nn - (i * (i - 1)) / 2 + (j - i);
}

__global__ void k_zero(float* ws) {
  int i = blockIdx.x * blockDim.x + threadIdx.x;
  if (i < Nn * Nn) ws[OFF_AGG + i] = 0.f;
  if (i < Nn) ws[OFF_DEG + i] = 0.f;
  if (i == 0) ws[OFF_REC] = 0.f;
}

__global__ void k_deg(const int* ei, float* ws) {
  int i = blockIdx.x * blockDim.x + threadIdx.x;
  if (i < NE) atomicAdd(&ws[OFF_DEG + ei[NE + i]], 1.f);  // dst
  if (i < Nn) atomicAdd(&ws[OFF_DEG + i], 1.f);           // self-loop
}

__global__ void k_dega(const float* A, float* ws) {
  int i = threadIdx.x;
  if (i < Nn) {
    float s = 0.f;
    for (int j = 0; j < Nn; ++j) s += A[i * Nn + j];  // exact: 0/1 values
    ws[OFF_DEGA + i] = s;
  }
}

__global__ void k_agg(const int* ei, float* ws) {
  int i = blockIdx.x * blockDim.x + threadIdx.x;
  if (i < NE) {
    int s = ei[i], d = ei[NE + i];
    float c = (1.f / sqrtf(ws[OFF_DEG + s])) * (1.f / sqrtf(ws[OFF_DEG + d]));
    atomicAdd(&ws[OFF_AGG + d * Nn + s], c);
  }
  if (i < Nn) {
    float di = 1.f / sqrtf(ws[OFF_DEG + i]);
    atomicAdd(&ws[OFF_AGG + i * Nn + i], di * di);
  }
}

// out[r][c] = sum_k in[r][k]*W[k][c]   (out is Nn x HIDF, blockDim=256)
__global__ void k_mm(const float* inp, const float* W, float* out, int K) {
  int r = blockIdx.x, c = threadIdx.x;
  __shared__ float row[HIDF];
  if (c < K) row[c] = inp[r * K + c];
  __syncthreads();
  float s = 0.f;
  for (int k = 0; k < K; ++k) s += row[k] * W[k * HIDF + c];
  out[r * HIDF + c] = s;
}

// out[r][c] = bias[c] + sum_j AGG[r][j]*H[j][c]
__global__ void k_aggmul(const float* ws_all, const float* H, const float* bias, float* out) {
  int r = blockIdx.x, c = threadIdx.x;
  __shared__ float ar[Nn];
  if (c < Nn) ar[c] = ws_all[OFF_AGG + r * Nn + c];
  __syncthreads();
  float s = bias[c];
  for (int j = 0; j < Nn; ++j) s += ar[j] * H[j * HIDF + c];
  out[r * HIDF + c] = s;
}

// per-column batchnorm (over Nn rows) + relu; optional column-sum pooling
__global__ void k_bn(const float* G, const float* gam, const float* bet,
                     float* Hout, float* pool, int do_pool) {
  int c = blockIdx.x, t = threadIdx.x;  // blockDim = 128
  __shared__ float red[128];
  float v = (t < Nn) ? G[t * HIDF + c] : 0.f;
  red[t] = v;
  __syncthreads();
  for (int s = 64; s >= 1; s >>= 1) { if (t < s) red[t] += red[t + s]; __syncthreads(); }
  float mean = red[0] / Nn;
  __syncthreads();
  float d = (t < Nn) ? (v - mean) : 0.f;
  red[t] = d * d;
  __syncthreads();
  for (int s = 64; s >= 1; s >>= 1) { if (t < s) red[t] += red[t + s]; __syncthreads(); }
  float var = red[0] / Nn;
  float y = (v - mean) * (1.f / sqrtf(var + 1e-5f)) * gam[c] + bet[c];
  y = fmaxf(y, 0.f);
  if (t < Nn) Hout[t * HIDF + c] = y;
  if (do_pool) {
    __syncthreads();
    red[t] = (t < Nn) ? y : 0.f;
    __syncthreads();
    for (int s = 64; s >= 1; s >>= 1) { if (t < s) red[t] += red[t + s]; __syncthreads(); }
    if (t == 0) pool[c] = red[0];
  }
}

// VAE head: mu/lv/z/d1 + KL  (1 block, 256 threads)
__global__ void k_head(const float* muw, const float* mub, const float* lvw, const float* lvb,
                       const float* d1w, const float* d1b, const float* eps, float* ws) {
  int t = threadIdx.x;
  __shared__ float g[HIDF];
  __shared__ float z[ZD];
  __shared__ float red[64];
  g[t] = ws[OFF_POOL + t];
  __syncthreads();
  float mu = 0.f, lv = 0.f;
  if (t < ZD) {
    mu = mub[t]; lv = lvb[t];
    for (int k = 0; k < HIDF; ++k) { mu += g[k] * muw[k * ZD + t]; lv += g[k] * lvw[k * ZD + t]; }
    ws[OFF_MU + t] = mu; ws[OFF_LV + t] = lv;
    z[t] = mu + eps[t] * expf(0.5f * lv);
  }
  __syncthreads();
  float s = d1b[t];
  for (int k = 0; k < ZD; ++k) s += z[k] * d1w[k * HIDF + t];
  ws[OFF_D1 + t] = fmaxf(s, 0.f);
  if (t < ZD) red[t] = 1.f + lv - mu * mu - expf(lv);
  __syncthreads();
  for (int st = 32; st >= 1; st >>= 1) { if (t < st) red[t] += red[t + st]; __syncthreads(); }
  if (t == 0) ws[OFF_KL] = -0.5f * red[0] / ZD;
}

// vec = relu(z@dec1)@dec2 + b  (19 blocks x 256)
__global__ void k_vec(const float* w, const float* b, float* ws) {
  __shared__ float d1[HIDF];
  d1[threadIdx.x] = ws[OFF_D1 + threadIdx.x];
  __syncthreads();
  int c = blockIdx.x * blockDim.x + threadIdx.x;
  if (c < TRIN) {
    float s = b[c];
    for (int k = 0; k < HIDF; ++k) s += d1[k] * w[k * TRIN + c];
    ws[OFF_VEC + c] = s;
  }
}

// B = sigmoid(sym logits), Bd diag, degB row sums  (96 blocks x 128)
__global__ void k_B(float* ws) {
  int a = blockIdx.x, t = threadIdx.x;
  __shared__ float red[128];
  float Bab = 0.f;
  if (t < Nn) {
    int i = min(a, t), j = max(a, t);
    float l = ws[OFF_VEC + tri_idx(i, j)];
    Bab = 1.f / (1.f + expf(-l));
    ws[OFF_B + a * Nn + t] = Bab;
    if (t == a) ws[OFF_BD + a] = Bab;
  }
  red[t] = Bab;
  __syncthreads();
  for (int s = 64; s >= 1; s >>= 1) { if (t < s) red[t] += red[t + s]; __syncthreads(); }
  if (t == 0) ws[OFF_DEGB + a] = red[0];
}

// Q row-major [a][b]; D transposed [a][i]
__global__ void k_QD(const float* A, float* ws) {
  int a = blockIdx.x, t = threadIdx.x;
  if (t < Nn) {
    float Bda = ws[OFF_BD + a];
    float q = ws[OFF_B + a * Nn + t] * Bda * ws[OFF_BD + t];
    if (t == a) q = 0.f;
    ws[OFF_Q + a * Nn + t] = q;
    float Adt = A[t * Nn + t];
    ws[OFF_DT + a * Nn + t] = Adt * Bda / (fabsf(ws[OFF_DEGA + t] - ws[OFF_DEGB + a]) + 1.f);
  }
}

// BCE-with-logits sum over upper triangle (96 blocks x 128, atomic partials)
__global__ void k_rec(const float* A, float* ws) {
  int i = blockIdx.x, t = threadIdx.x;
  __shared__ float red[128];
  float s = 0.f;
  for (int j = i + t; j < Nn; j += 128) {
    float v = ws[OFF_VEC + tri_idx(i, j)];
    float tt = A[i * Nn + j];
    s += fmaxf(v, 0.f) - v * tt + log1pf(expf(-fabsf(v)));
  }
  red[t] = s;
  __syncthreads();
  for (int st = 64; st >= 1; st >>= 1) { if (t < st) red[t] += red[t + st]; __syncthreads(); }
  if (t == 0) atomicAdd(&ws[OFF_REC], red[0]);
}

// Cooperative MPM: 96 blocks (one per column a) x 512 threads, 1 grid sync / iter.
// u stored as u[a*Nn+i] == X[i][a]. Deferred normalization: divide by prev norm.
__launch_bounds__(512)
__global__ void k_mpm(const float* A, float* ws, float* out) {
  cg::grid_group grid = cg::this_grid();
  const int a = blockIdx.x;
  const int tid = threadIdx.x;
  const int seg = tid >> 7;   // 0..3 (b/j range splits of 24)
  const int lid = tid & 127;  // 0..127 (j or i, valid < 96)
  __shared__ float Psh[Nn * 97];  // +1 pad: conflict-free stride-97 row reads
  __shared__ float Qrow[Nn];
  __shared__ float Dcol[Nn];
  __shared__ float Msh[Nn];
  __shared__ float part[4 * 128];
  __shared__ float red[128];

  for (int idx = tid; idx < Nn * Nn; idx += 512) {
    int i = idx / Nn, j = idx - (idx / Nn) * Nn;
    float p = A[i * Nn + j] * A[i * Nn + i] * A[j * Nn + j];
    if (i == j) p = 0.f;
    Psh[i * 97 + j] = p;
  }
  if (tid < Nn) {
    Qrow[tid] = ws[OFF_Q + a * Nn + tid];
    Dcol[tid] = ws[OFF_DT + a * Nn + tid];
    ws[OFF_U0 + a * Nn + tid] = 1.f / Nn;  // x0
  }
  if (tid == 0) ws[OFF_P0 + a] = (a == 0) ? 1.f : 0.f;  // sum==1 -> first divisor exactly 1
  grid.sync();

  float* ucur = ws + OFF_U0; float* unew = ws + OFF_U1;
  float* pcur = ws + OFF_P0; float* pnew = ws + OFF_P1;

  for (int it = 0; it < NITER; ++it) {
    // norm of previous unnormalized iterate (identical tree in every block)
    if (tid < 128) red[tid] = (tid < Nn) ? pcur[tid] : 0.f;
    __syncthreads();
    for (int s = 64; s >= 1; s >>= 1) { if (tid < s) red[tid] += red[tid + s]; __syncthreads(); }
    float nrm = sqrtf(red[0]);

    // M[j,a] = max_b Q[a,b]*u[j,b]; u[b*Nn+j] coalesced across j
    float m = 0.f;
    if (lid < Nn) {
      const float* up = ucur + seg * 24 * Nn + lid;
      #pragma unroll
      for (int bb = 0; bb < 24; ++bb)
        m = fmaxf(m, Qrow[seg * 24 + bb] * up[bb * Nn]);
    }
    part[seg * 128 + lid] = m;
    __syncthreads();
    if (tid < Nn)
      Msh[tid] = fmaxf(fmaxf(part[tid], part[128 + tid]),
                       fmaxf(part[256 + tid], part[384 + tid]));
    __syncthreads();

    // msg[i,a] = sum_j P[i,j]*M[j]
    float sacc = 0.f;
    if (lid < Nn) {
      #pragma unroll
      for (int jj = 0; jj < 24; ++jj) {
        int j = seg * 24 + jj;
        sacc += Psh[lid * 97 + j] * Msh[j];
      }
    }
    part[seg * 128 + lid] = sacc;
    __syncthreads();
    if (tid < Nn) {
      float msg = part[tid] + part[128 + tid] + part[256 + tid] + part[384 + tid];
      float xn = ucur[a * Nn + tid] * Dcol[tid] + msg;
      float val = xn / nrm;                 // deferred normalization
      unew[a * Nn + tid] = val;
      red[tid] = val * val;
    } else if (tid < 128) red[tid] = 0.f;
    __syncthreads();
    for (int s = 64; s >= 1; s >>= 1) { if (tid < s) red[tid] += red[tid + s]; __syncthreads(); }
    if (tid == 0) pnew[a] = red[0];
    grid.sync();
    float* tmp = ucur; ucur = unew; unew = tmp;
    tmp = pcur; pcur = pnew; pnew = tmp;
  }

  // final normalize + outputs
  if (tid < 128) red[tid] = (tid < Nn) ? pcur[tid] : 0.f;
  __syncthreads();
  for (int s = 64; s >= 1; s >>= 1) { if (tid < s) red[tid] += red[tid + s]; __syncthreads(); }
  float nrm = sqrtf(red[0]);
  if (tid < Nn) out[1 + tid * Nn + a] = ucur[a * Nn + tid] / nrm;  // X[i][a]
  if (a == 0 && tid == 0) out[0] = ws[OFF_REC] / TRIN + ws[OFF_KL];
}

extern "C" void kernel_launch(void* const* d_in, const int* in_sizes, int n_in,
                              void* d_out, int out_size, void* d_ws, size_t ws_size,
                              hipStream_t stream) {
  const float* x   = (const float*)d_in[0];
  const int*   ei  = (const int*)d_in[1];
  // d_in[2] = batch (all zeros) unused
  const float* A   = (const float*)d_in[3];
  const float* w1  = (const float*)d_in[4];
  const float* b1  = (const float*)d_in[5];
  const float* g1  = (const float*)d_in[6];
  const float* be1 = (const float*)d_in[7];
  const float* w2  = (const float*)d_in[8];
  const float* b2  = (const float*)d_in[9];
  const float* g2  = (const float*)d_in[10];
  const float* be2 = (const float*)d_in[11];
  const float* muw = (const float*)d_in[12];
  const float* mub = (const float*)d_in[13];
  const float* lvw = (const float*)d_in[14];
  const float* lvb = (const float*)d_in[15];
  const float* d1w = (const float*)d_in[16];
  const float* d1b = (const float*)d_in[17];
  const float* d2w = (const float*)d_in[18];
  const float* d2b = (const float*)d_in[19];
  const float* eps = (const float*)d_in[20];
  float* ws  = (float*)d_ws;
  float* out = (float*)d_out;

  k_zero<<<dim3(36), dim3(256), 0, stream>>>(ws);
  k_deg<<<dim3(8), dim3(256), 0, stream>>>(ei, ws);
  k_dega<<<dim3(1), dim3(128), 0, stream>>>(A, ws);
  k_agg<<<dim3(8), dim3(256), 0, stream>>>(ei, ws);

  // layer 1
  k_mm<<<dim3(Nn), dim3(256), 0, stream>>>(x, w1, ws + OFF_XW, INF);
  k_aggmul<<<dim3(Nn), dim3(256), 0, stream>>>(ws, ws + OFF_XW, b1, ws + OFF_G);
  k_bn<<<dim3(HIDF), dim3(128), 0, stream>>>(ws + OFF_G, g1, be1, ws + OFF_H1, ws + OFF_POOL, 0);
  // layer 2
  k_mm<<<dim3(Nn), dim3(256), 0, stream>>>(ws + OFF_H1, w2, ws + OFF_XW, HIDF);
  k_aggmul<<<dim3(Nn), dim3(256), 0, stream>>>(ws, ws + OFF_XW, b2, ws + OFF_G);
  k_bn<<<dim3(HIDF), dim3(128), 0, stream>>>(ws + OFF_G, g2, be2, ws + OFF_H1, ws + OFF_POOL, 1);

  k_head<<<dim3(1), dim3(256), 0, stream>>>(muw, mub, lvw, lvb, d1w, d1b, eps, ws);
  k_vec<<<dim3((TRIN + 255) / 256), dim3(256), 0, stream>>>(d2w, d2b, ws);
  k_B<<<dim3(Nn), dim3(128), 0, stream>>>(ws);
  k_QD<<<dim3(Nn), dim3(128), 0, stream>>>(A, ws);
  k_rec<<<dim3(Nn), dim3(128), 0, stream>>>(A, ws);

  {
    const float* Aarg = A; float* wsArg = ws; float* outArg = out;
    void* args[3] = { (void*)&Aarg, (void*)&wsArg, (void*)&outArg };
    hipLaunchCooperativeKernel((void*)k_mpm, dim3(Nn), dim3(512), args, 0, stream);
  }
}

// Round 2
// 876.820 us; speedup vs baseline: 1.0502x; 1.0502x over previous
//
#include <hip/hip_runtime.h>
#include <cmath>

#define Nn 96
#define NB 32          // blocks
#define NT 512         // threads/block
#define GT (NB*NT)
#define CPB 3          // columns per block (NB*CPB = 96)
#define MAXD 40
#define NE 2048
#define TRIN 4656
#define NITER 50
#define AGENT __HIP_MEMORY_SCOPE_AGENT

// workspace layout (floats)
enum {
  OFF_FLAGS = 0,                    // 32 (int) barrier flags   [memset 0]
  OFF_DEG   = 32,                   // 96                       [memset 0]
  OFF_RECP  = 128,                  // 96
  OFF_AGG   = 224,                  // 9216                     [memset 0]
  OFF_DEGA  = 9440,                 // 96
  OFF_XW    = 9536,                 // 96*256
  OFF_G     = 34112,                // 96*256
  OFF_H1    = 58688,                // 96*256
  OFF_POOL  = 83264,                // 256
  OFF_MU    = 83520,                // 64
  OFF_LV    = 83584,                // 64
  OFF_Z     = 83648,                // 64
  OFF_D1    = 83712,                // 256
  OFF_KL    = 83968,                // 1
  OFF_REC   = 83969,                // 1
  OFF_VEC   = 83972,                // 4656
  OFF_B     = 88628,                // 9216
  OFF_BD    = 97844,                // 96
  OFF_DEGB  = 97940,                // 96
  OFF_Q     = 98036,                // 9216  row-major [a][b]
  OFF_X0    = 107252,               // 9216  X stored transposed: Xg[a*96+i] = X[i][a]
  OFF_X1    = 116468,               // 9216
  OFF_PART  = 125684,               // 32 norm partials per block
  WS_END    = 125716
};
#define MEMSET_FLOATS (OFF_AGG + Nn*Nn)   // covers FLAGS, DEG, RECP, AGG

__device__ __forceinline__ int tri_idx(int i, int j) {  // i <= j
  return i * Nn - (i * (i - 1)) / 2 + (j - i);
}

// distributed-flag grid barrier: each block release-stores its own slot,
// wave-0 lanes acquire-poll all NB slots concurrently (no contended RMW).
__device__ __forceinline__ void gbar(float* ws, int target) {
  int* flags = (int*)ws;  // OFF_FLAGS
  __threadfence();        // agent-scope release of this thread's global writes
  __syncthreads();
  if (threadIdx.x < NB) {
    if (threadIdx.x == 0)
      __hip_atomic_store(&flags[blockIdx.x], target, __ATOMIC_RELEASE, AGENT);
    while (__hip_atomic_load(&flags[threadIdx.x], __ATOMIC_ACQUIRE, AGENT) < target) {}
  }
  __syncthreads();
}

__global__ __launch_bounds__(NT)
void k_fused(const float* x, const int* ei, const float* A,
             const float* w1, const float* b1, const float* g1, const float* be1,
             const float* w2, const float* b2, const float* g2, const float* be2,
             const float* muw, const float* mub, const float* lvw, const float* lvb,
             const float* d1w, const float* d1b, const float* d2w, const float* d2b,
             const float* eps, float* ws, float* out) {
  __shared__ float XT[Nn * 97];      // XT[a*97+i] = X[i][a]
  __shared__ float Qsh[CPB * Nn];
  __shared__ float Msh[CPB * Nn];
  __shared__ float part[12 * Nn];
  __shared__ int   nbr[Nn * MAXD];
  __shared__ int   ncnt[Nn];
  __shared__ float red[NT];
  __shared__ float sc[4];

  const int tid  = threadIdx.x;
  const int bid  = blockIdx.x;
  const int gtid = bid * NT + tid;
  int bt = 0;

  // ---------------- Ph0: degrees (edge-based) + degA (A row sums) ----------------
  if (gtid < NE) atomicAdd(&ws[OFF_DEG + ei[NE + gtid]], 1.f);
  else if (gtid < NE + Nn) atomicAdd(&ws[OFF_DEG + (gtid - NE)], 1.f);
  else if (gtid < NE + 2 * Nn) {
    int i = gtid - NE - Nn; float s = 0.f;
    for (int j = 0; j < Nn; ++j) s += A[i * Nn + j];
    ws[OFF_DEGA + i] = s;
  }
  gbar(ws, ++bt);

  // ---------------- Ph1: AGG (normalized adjacency) ----------------
  if (gtid < NE) {
    int s = ei[gtid], d = ei[NE + gtid];
    float c = (1.f / sqrtf(ws[OFF_DEG + s])) * (1.f / sqrtf(ws[OFF_DEG + d]));
    atomicAdd(&ws[OFF_AGG + d * Nn + s], c);
  } else if (gtid < NE + Nn) {
    int i = gtid - NE; float di = 1.f / sqrtf(ws[OFF_DEG + i]);
    atomicAdd(&ws[OFF_AGG + i * Nn + i], di * di);
  }
  gbar(ws, ++bt);

  // ---------------- Ph2: XW = x @ w1  (96x256, K=64) ----------------
  for (int o = gtid; o < Nn * 256; o += GT) {
    int r = o >> 8, c = o & 255;
    float s = 0.f;
    for (int k = 0; k < 64; ++k) s += x[r * 64 + k] * w1[k * 256 + c];
    ws[OFF_XW + o] = s;
  }
  gbar(ws, ++bt);

  // ---------------- Ph3: G = AGG @ XW + b1 ----------------
  for (int o = gtid; o < Nn * 256; o += GT) {
    int r = o >> 8, c = o & 255;
    float s = b1[c];
    for (int k = 0; k < Nn; ++k) s += ws[OFF_AGG + r * Nn + k] * ws[OFF_XW + k * 256 + c];
    ws[OFF_G + o] = s;
  }
  gbar(ws, ++bt);

  // ---------------- Ph4: bn1 + relu -> H1 ----------------
  if (gtid < 256) {
    int c = gtid; float m = 0.f;
    for (int r = 0; r < Nn; ++r) m += ws[OFF_G + r * 256 + c];
    m /= (float)Nn;
    float v = 0.f;
    for (int r = 0; r < Nn; ++r) { float d = ws[OFF_G + r * 256 + c] - m; v += d * d; }
    v /= (float)Nn;
    float rs = 1.f / sqrtf(v + 1e-5f);
    float gg = g1[c], bb = be1[c];
    for (int r = 0; r < Nn; ++r) {
      float y = (ws[OFF_G + r * 256 + c] - m) * rs * gg + bb;
      ws[OFF_H1 + r * 256 + c] = fmaxf(y, 0.f);
    }
  }
  gbar(ws, ++bt);

  // ---------------- Ph5: XW2 = H1 @ w2 (K=256) ----------------
  for (int o = gtid; o < Nn * 256; o += GT) {
    int r = o >> 8, c = o & 255;
    float s = 0.f;
    for (int k = 0; k < 256; ++k) s += ws[OFF_H1 + r * 256 + k] * w2[k * 256 + c];
    ws[OFF_XW + o] = s;
  }
  gbar(ws, ++bt);

  // ---------------- Ph6: G2 = AGG @ XW2 + b2 ----------------
  for (int o = gtid; o < Nn * 256; o += GT) {
    int r = o >> 8, c = o & 255;
    float s = b2[c];
    for (int k = 0; k < Nn; ++k) s += ws[OFF_AGG + r * Nn + k] * ws[OFF_XW + k * 256 + c];
    ws[OFF_G + o] = s;
  }
  gbar(ws, ++bt);

  // ---------------- Ph7: bn2 + relu + sum-pool ----------------
  if (gtid < 256) {
    int c = gtid; float m = 0.f;
    for (int r = 0; r < Nn; ++r) m += ws[OFF_G + r * 256 + c];
    m /= (float)Nn;
    float v = 0.f;
    for (int r = 0; r < Nn; ++r) { float d = ws[OFF_G + r * 256 + c] - m; v += d * d; }
    v /= (float)Nn;
    float rs = 1.f / sqrtf(v + 1e-5f);
    float gg = g2[c], bb = be2[c], p = 0.f;
    for (int r = 0; r < Nn; ++r) {
      float y = (ws[OFF_G + r * 256 + c] - m) * rs * gg + bb;
      p += fmaxf(y, 0.f);
    }
    ws[OFF_POOL + c] = p;
  }
  gbar(ws, ++bt);

  // ---------------- Ph8: mu / lv / z ----------------
  if (gtid < 64) {
    int t = gtid; float mu = mub[t], lv = lvb[t];
    for (int k = 0; k < 256; ++k) {
      float g = ws[OFF_POOL + k];
      mu += g * muw[k * 64 + t];
      lv += g * lvw[k * 64 + t];
    }
    ws[OFF_MU + t] = mu; ws[OFF_LV + t] = lv;
    ws[OFF_Z + t] = mu + eps[t] * expf(0.5f * lv);
  }
  gbar(ws, ++bt);

  // ---------------- Ph9: d1 = relu(z @ dec1 + b) ; KL ----------------
  if (gtid < 256) {
    int c = gtid; float s = d1b[c];
    for (int k = 0; k < 64; ++k) s += ws[OFF_Z + k] * d1w[k * 256 + c];
    ws[OFF_D1 + c] = fmaxf(s, 0.f);
  } else if (gtid == 256) {
    float s = 0.f;
    for (int t = 0; t < 64; ++t) {
      float mu = ws[OFF_MU + t], lv = ws[OFF_LV + t];
      s += 1.f + lv - mu * mu - expf(lv);
    }
    ws[OFF_KL] = -0.5f * s / 64.f;
  }
  gbar(ws, ++bt);

  // ---------------- Ph10: vec = d1 @ dec2 + b (4656 cols, 146/block) ----------------
  {
    int c0 = bid * 146;
    int c = c0 + tid;
    if (tid < 146 && c < TRIN) {
      float s = d2b[c];
      for (int k = 0; k < 256; ++k) s += ws[OFF_D1 + k] * d2w[k * TRIN + c];
      ws[OFF_VEC + c] = s;
    }
  }
  gbar(ws, ++bt);

  // ---------------- Ph11: B = sigmoid(sym logits) ; rec row partials ----------------
  for (int o = gtid; o < Nn * Nn; o += GT) {
    int a = o / Nn, t = o - (o / Nn) * Nn;
    int i = a < t ? a : t, j = a < t ? t : a;
    float l = ws[OFF_VEC + tri_idx(i, j)];
    ws[OFF_B + o] = 1.f / (1.f + expf(-l));
  }
  if (gtid < Nn) {
    float s = 0.f;
    for (int j = gtid; j < Nn; ++j) {
      float v = ws[OFF_VEC + tri_idx(gtid, j)];
      float tt = A[gtid * Nn + j];
      s += fmaxf(v, 0.f) - v * tt + log1pf(expf(-fabsf(v)));
    }
    ws[OFF_RECP + gtid] = s;
  }
  gbar(ws, ++bt);

  // ---------------- Ph12: Bd, degB, REC total ----------------
  if (gtid < Nn) {
    int a = gtid; float s = 0.f;
    for (int b = 0; b < Nn; ++b) s += ws[OFF_B + a * Nn + b];
    ws[OFF_DEGB + a] = s;
    ws[OFF_BD + a] = ws[OFF_B + a * Nn + a];
  } else if (gtid == Nn) {
    float s = 0.f;
    for (int i = 0; i < Nn; ++i) s += ws[OFF_RECP + i];
    ws[OFF_REC] = s;
  }
  gbar(ws, ++bt);

  // ---------------- Ph13: Q ; X0 init ; norm partials init ----------------
  for (int o = gtid; o < Nn * Nn; o += GT) {
    int a = o / Nn, b = o - (o / Nn) * Nn;
    float q = (a == b) ? 0.f : ws[OFF_B + o] * ws[OFF_BD + a] * ws[OFF_BD + b];
    ws[OFF_Q + o] = q;
  }
  for (int o = gtid; o < Nn * Nn; o += GT) ws[OFF_X0 + o] = 1.f / (float)Nn;
  if (gtid < NB) ws[OFF_PART + gtid] = (gtid == 0) ? 1.f : 0.f;  // ||x0||^2 = 1 exactly
  gbar(ws, ++bt);

  // ---------------- per-block static prep (no global writes) ----------------
  const int a0 = bid * CPB;
  if (tid < CPB * Nn) Qsh[tid] = ws[OFF_Q + a0 * Nn + tid];  // tid = c*96+b
  float Dreg = 0.f;
  if (tid < CPB * Nn) {
    int c = tid / Nn, i = tid - c * Nn;
    Dreg = A[i * Nn + i] * ws[OFF_BD + a0 + c] /
           (fabsf(ws[OFF_DEGA + i] - ws[OFF_DEGB + a0 + c]) + 1.f);
  }
  if (tid < Nn) {
    int cnt = 0;
    for (int j = 0; j < Nn; ++j)
      if (j != tid && A[tid * Nn + j] != 0.f && cnt < MAXD) nbr[tid * MAXD + cnt++] = j;
    ncnt[tid] = cnt;
  }
  __syncthreads();

  // ---------------- MPM: 50 iterations, ONE barrier each ----------------
  float* Xcur = ws + OFF_X0;
  float* Xnew = ws + OFF_X1;

  for (int it = 0; it < NITER; ++it) {
    // norm of previous unnormalized iterate (deferred normalization)
    if (tid < NB) red[tid] = ws[OFF_PART + tid];
    // stage Xcur -> LDS transposed (Xg[a*96+i] -> XT[a*97+i]), float4
    {
      const float4* X4 = (const float4*)Xcur;
      for (int o4 = tid; o4 < (Nn * Nn) / 4; o4 += NT) {
        int a = o4 / 24;
        int i4 = (o4 - a * 24) * 4;
        float4 v = X4[o4];
        int base = a * 97 + i4;
        XT[base] = v.x; XT[base + 1] = v.y; XT[base + 2] = v.z; XT[base + 3] = v.w;
      }
    }
    __syncthreads();
    if (tid == 0) {
      float s = 0.f;
      for (int k = 0; k < NB; ++k) s += red[k];
      sc[0] = sqrtf(s);
    }
    __syncthreads();
    float nrm = sc[0];

    // M[j,a0+c] = max_b Q[a0+c,b] * X[j,b] ; threads (bseg,j), each X read used CPB times
    if (tid < 4 * Nn) {
      int bseg = tid / Nn, j = tid - bseg * Nn;
      int b0 = bseg * 24;
      float m0 = 0.f, m1 = 0.f, m2 = 0.f;
      #pragma unroll
      for (int bb = 0; bb < 24; ++bb) {
        float xv = XT[(b0 + bb) * 97 + j];
        m0 = fmaxf(m0, Qsh[b0 + bb] * xv);
        m1 = fmaxf(m1, Qsh[Nn + b0 + bb] * xv);
        m2 = fmaxf(m2, Qsh[2 * Nn + b0 + bb] * xv);
      }
      part[(bseg * 3 + 0) * Nn + j] = m0;
      part[(bseg * 3 + 1) * Nn + j] = m1;
      part[(bseg * 3 + 2) * Nn + j] = m2;
    }
    __syncthreads();
    if (tid < CPB * Nn) {
      int c = tid / Nn, j = tid - c * Nn;
      Msh[c * Nn + j] = fmaxf(fmaxf(part[c * Nn + j], part[(3 + c) * Nn + j]),
                              fmaxf(part[(6 + c) * Nn + j], part[(9 + c) * Nn + j]));
    }
    __syncthreads();

    // msg + update + norm partial
    float val = 0.f;
    if (tid < CPB * Nn) {
      int c = tid / Nn, i = tid - c * Nn;
      float s = 0.f;
      int nc = ncnt[i];
      for (int k = 0; k < nc; ++k) s += Msh[c * Nn + nbr[i * MAXD + k]];
      float xo = XT[(a0 + c) * 97 + i];
      val = (xo * Dreg + s) / nrm;
      Xnew[(a0 + c) * Nn + i] = val;   // coalesced: 3 contiguous rows of 96
    }
    red[tid] = val * val;
    __syncthreads();
    for (int st = 256; st >= 1; st >>= 1) {
      if (tid < st) red[tid] += red[tid + st];
      __syncthreads();
    }
    if (tid == 0) ws[OFF_PART + bid] = red[0];
    gbar(ws, ++bt);
    float* tmp = Xcur; Xcur = Xnew; Xnew = tmp;
  }

  // ---------------- final normalize + outputs ----------------
  if (tid < NB) red[tid] = ws[OFF_PART + tid];
  __syncthreads();
  if (tid == 0) {
    float s = 0.f;
    for (int k = 0; k < NB; ++k) s += red[k];
    sc[0] = sqrtf(s);
  }
  __syncthreads();
  float nrm = sc[0];
  for (int o = gtid; o < Nn * Nn; o += GT) {
    int i = o / Nn, a = o - (o / Nn) * Nn;
    out[1 + o] = Xcur[a * Nn + i] / nrm;   // out[1 + i*96 + a] = X[i][a]
  }
  if (gtid == 0) out[0] = ws[OFF_REC] / (float)TRIN + ws[OFF_KL];
}

extern "C" void kernel_launch(void* const* d_in, const int* in_sizes, int n_in,
                              void* d_out, int out_size, void* d_ws, size_t ws_size,
                              hipStream_t stream) {
  const float* x   = (const float*)d_in[0];
  const int*   ei  = (const int*)d_in[1];
  const float* A   = (const float*)d_in[3];
  const float* w1  = (const float*)d_in[4];
  const float* b1  = (const float*)d_in[5];
  const float* g1  = (const float*)d_in[6];
  const float* be1 = (const float*)d_in[7];
  const float* w2  = (const float*)d_in[8];
  const float* b2  = (const float*)d_in[9];
  const float* g2  = (const float*)d_in[10];
  const float* be2 = (const float*)d_in[11];
  const float* muw = (const float*)d_in[12];
  const float* mub = (const float*)d_in[13];
  const float* lvw = (const float*)d_in[14];
  const float* lvb = (const float*)d_in[15];
  const float* d1w = (const float*)d_in[16];
  const float* d1b = (const float*)d_in[17];
  const float* d2w = (const float*)d_in[18];
  const float* d2b = (const float*)d_in[19];
  const float* eps = (const float*)d_in[20];
  float* ws  = (float*)d_ws;
  float* out = (float*)d_out;

  // zero barrier flags, DEG, AGG (atomically accumulated)
  hipMemsetAsync(ws, 0, MEMSET_FLOATS * sizeof(float), stream);

  void* args[] = {
    (void*)&x, (void*)&ei, (void*)&A,
    (void*)&w1, (void*)&b1, (void*)&g1, (void*)&be1,
    (void*)&w2, (void*)&b2, (void*)&g2, (void*)&be2,
    (void*)&muw, (void*)&mub, (void*)&lvw, (void*)&lvb,
    (void*)&d1w, (void*)&d1b, (void*)&d2w, (void*)&d2b,
    (void*)&eps, (void*)&ws, (void*)&out
  };
  hipLaunchCooperativeKernel((void*)k_fused, dim3(NB), dim3(NT), args, 0, stream);
}

// Round 4
// 615.763 us; speedup vs baseline: 1.4954x; 1.4240x over previous
//
#include <hip/hip_runtime.h>
#include <cmath>

#define Nn 96
#define NB 32
#define NT 512
#define GT (NB*NT)
#define MAXD 40
#define NE 2048
#define TRIN 4656
#define NITER 50
#define AGENT __HIP_MEMORY_SCOPE_AGENT

// workspace layout (floats); only FLAGS needs pre-zeroing
enum {
  OFF_FLAGS = 0,     // 32 ints
  OFF_POOL  = 32,    // 256
  OFF_D1    = 288,   // 256
  OFF_KL    = 544,   // 1
  OFF_RECP  = 546,   // 96
  OFF_VEC   = 642,   // 4656
  OFF_XW    = 5298,  // 24576 (layer1 XW, then reused as XW2)
  OFF_H1    = 29874, // 24576
  OFF_B     = 54450, // 9216
  OFF_BD    = 63666, // 96
  OFF_DEGB  = 63762, // 96
  OFF_Q     = 63858, // 9216
  OFF_X0    = 73074, // 9216 (even -> 8B aligned)
  OFF_X1    = 82290, // 9216 (even)
  OFF_PART  = 91506, // 32
  WS_END    = 91538
};

__device__ __forceinline__ int tri_idx(int i, int j) {  // i <= j
  return i * Nn - (i * (i - 1)) / 2 + (j - i);
}

// ---- MALL-coherent accessors: relaxed agent atomics (sc0+sc1, no fences) ----
__device__ __forceinline__ float gload(const float* p) {
  return __hip_atomic_load(p, __ATOMIC_RELAXED, AGENT);
}
__device__ __forceinline__ void gstore(float* p, float v) {
  __hip_atomic_store(p, v, __ATOMIC_RELAXED, AGENT);
}
__device__ __forceinline__ void gload2(const float* p, float& x, float& y) {
  unsigned long long u =
      __hip_atomic_load((const unsigned long long*)p, __ATOMIC_RELAXED, AGENT);
  union { unsigned long long u; float f[2]; } c; c.u = u;
  x = c.f[0]; y = c.f[1];
}

// fence-free grid barrier: per-wave vmcnt drain (stores acked at MALL),
// relaxed flag store, 32 coalesced relaxed polls. No wbl2 / buffer_inv.
__device__ __forceinline__ void gbar(int* flags, int target) {
  asm volatile("s_waitcnt vmcnt(0)" ::: "memory");
  __syncthreads();
  if (threadIdx.x == 0)
    __hip_atomic_store(&flags[blockIdx.x], target, __ATOMIC_RELAXED, AGENT);
  if (threadIdx.x < NB)
    while (__hip_atomic_load(&flags[threadIdx.x], __ATOMIC_RELAXED, AGENT) < target) {}
  __syncthreads();
}

__device__ __forceinline__ float wsum64(float v) {
  #pragma unroll
  for (int m = 32; m >= 1; m >>= 1) v += __shfl_xor(v, m, 64);
  return v;
}

__global__ __launch_bounds__(NT)
void k_fused(const float* x, const int* ei, const float* A,
             const float* w1, const float* b1, const float* g1, const float* be1,
             const float* w2, const float* b2, const float* g2, const float* be2,
             const float* muw, const float* mub, const float* lvw, const float* lvb,
             const float* d1w, const float* d1b, const float* d2w, const float* d2b,
             const float* eps, float* ws, float* out) {
  __shared__ float SBIG[Nn * 97];   // AGG (stride 97) in prologue; XT in MPM
  __shared__ float SAUX[768];       // staging: x rows / XW cols / H1 rows / pool / d1
  __shared__ float SAUX2[768];      // G cols (bn) / mu-lv-z (head) / wave partials (MPM)
  __shared__ float Qsh[3 * Nn];
  __shared__ float Msh[3 * Nn];
  __shared__ float partM[12 * Nn];
  __shared__ float degl[Nn];
  __shared__ float DEGAl[Nn];
  __shared__ float mv[16];
  __shared__ float sc[4];
  __shared__ unsigned char nbr[Nn * MAXD];
  __shared__ int ncnt[Nn];

  const int tid  = threadIdx.x;
  const int bid  = blockIdx.x;
  const int gtid = bid * NT + tid;
  int* flags = (int*)ws;
  int bt = 0;

  // ================= Ph1: local deg/AGG/degA/nbr (LDS) + XW = x@w1 =================
  for (int o = tid; o < Nn * 97; o += NT) SBIG[o] = 0.f;
  if (tid < Nn) degl[tid] = 0.f;
  __syncthreads();
  for (int e = tid; e < NE; e += NT) atomicAdd(&degl[ei[NE + e]], 1.f);
  if (tid < Nn) atomicAdd(&degl[tid], 1.f);
  __syncthreads();
  for (int e = tid; e < NE; e += NT) {
    int s = ei[e], d = ei[NE + e];
    float c = (1.f / sqrtf(degl[s])) * (1.f / sqrtf(degl[d]));
    atomicAdd(&SBIG[d * 97 + s], c);
  }
  if (tid < Nn) atomicAdd(&SBIG[tid * 97 + tid], 1.f / degl[tid]);
  if (tid < Nn) {
    float s = 0.f;
    for (int j = 0; j < Nn; ++j) s += A[tid * Nn + j];
    DEGAl[tid] = s;
    int cnt = 0;
    for (int j = 0; j < Nn; ++j)
      if (j != tid && A[tid * Nn + j] != 0.f && cnt < MAXD)
        nbr[tid * MAXD + cnt++] = (unsigned char)j;
    ncnt[tid] = cnt;
  }
  {
    const int r0 = bid * 3;
    if (tid < 192) SAUX[tid] = x[r0 * 64 + tid];   // 3 rows of x
    __syncthreads();
    for (int o = tid; o < 3 * 256; o += NT) {
      int rl = o >> 8, c = o & 255;
      float s = 0.f;
      #pragma unroll 8
      for (int k = 0; k < 64; ++k) s += SAUX[rl * 64 + k] * w1[k * 256 + c];
      gstore(&ws[OFF_XW + (r0 + rl) * 256 + c], s);
    }
  }
  gbar(flags, ++bt);

  // ================= Ph2: G = AGG@XW + b1 (8 cols/block) + bn1 -> H1 =================
  {
    const int c0 = bid * 8;
    for (int o = tid; o < 768; o += NT) {
      int cl = o / Nn, k = o - cl * Nn;
      SAUX[o] = gload(&ws[OFF_XW + k * 256 + c0 + cl]);
    }
    __syncthreads();
    for (int o = tid; o < 768; o += NT) {
      int cl = o / Nn, r = o - cl * Nn;
      float s = b1[c0 + cl];
      #pragma unroll 8
      for (int k = 0; k < Nn; ++k) s += SBIG[r * 97 + k] * SAUX[cl * Nn + k];
      SAUX2[cl * Nn + r] = s;
    }
    __syncthreads();
    if (tid < 8) {
      float m = 0.f;
      for (int r = 0; r < Nn; ++r) m += SAUX2[tid * Nn + r];
      m /= (float)Nn;
      float v = 0.f;
      for (int r = 0; r < Nn; ++r) { float d = SAUX2[tid * Nn + r] - m; v += d * d; }
      v /= (float)Nn;
      mv[tid * 2] = m; mv[tid * 2 + 1] = 1.f / sqrtf(v + 1e-5f);
    }
    __syncthreads();
    for (int o = tid; o < 768; o += NT) {
      int cl = o / Nn, r = o - cl * Nn; int c = c0 + cl;
      float y = (SAUX2[o] - mv[cl * 2]) * mv[cl * 2 + 1] * g1[c] + be1[c];
      gstore(&ws[OFF_H1 + r * 256 + c], fmaxf(y, 0.f));
    }
  }
  gbar(flags, ++bt);

  // ================= Ph3: XW2 = H1@w2 (3 rows/block) -> OFF_XW =================
  {
    const int r0 = bid * 3;
    for (int o = tid; o < 768; o += NT)
      SAUX[o] = gload(&ws[OFF_H1 + r0 * 256 + o]);   // 3 rows contiguous
    __syncthreads();
    for (int o = tid; o < 768; o += NT) {
      int rl = o >> 8, c = o & 255;
      float s = 0.f;
      #pragma unroll 4
      for (int k = 0; k < 256; ++k) s += SAUX[rl * 256 + k] * w2[k * 256 + c];
      gstore(&ws[OFF_XW + (r0 + rl) * 256 + c], s);
    }
  }
  gbar(flags, ++bt);

  // ================= Ph4: G2 = AGG@XW2 + b2 (8 cols) + bn2 + pool =================
  {
    const int c0 = bid * 8;
    for (int o = tid; o < 768; o += NT) {
      int cl = o / Nn, k = o - cl * Nn;
      SAUX[o] = gload(&ws[OFF_XW + k * 256 + c0 + cl]);
    }
    __syncthreads();
    for (int o = tid; o < 768; o += NT) {
      int cl = o / Nn, r = o - cl * Nn;
      float s = b2[c0 + cl];
      #pragma unroll 8
      for (int k = 0; k < Nn; ++k) s += SBIG[r * 97 + k] * SAUX[cl * Nn + k];
      SAUX2[cl * Nn + r] = s;
    }
    __syncthreads();
    if (tid < 8) {
      int c = c0 + tid;
      float m = 0.f;
      for (int r = 0; r < Nn; ++r) m += SAUX2[tid * Nn + r];
      m /= (float)Nn;
      float v = 0.f;
      for (int r = 0; r < Nn; ++r) { float d = SAUX2[tid * Nn + r] - m; v += d * d; }
      v /= (float)Nn;
      float rs = 1.f / sqrtf(v + 1e-5f);
      float gg = g2[c], bb = be2[c], p = 0.f;
      for (int r = 0; r < Nn; ++r)
        p += fmaxf((SAUX2[tid * Nn + r] - m) * rs * gg + bb, 0.f);
      gstore(&ws[OFF_POOL + c], p);
    }
  }
  gbar(flags, ++bt);

  // ================= Ph5: VAE head (block 0) =================
  if (bid == 0) {
    if (tid < 256) SAUX[tid] = gload(&ws[OFF_POOL + tid]);
    __syncthreads();
    if (tid < 64) {
      float mu = mub[tid], lv = lvb[tid];
      for (int k = 0; k < 256; ++k) {
        float g = SAUX[k];
        mu += g * muw[k * 64 + tid];
        lv += g * lvw[k * 64 + tid];
      }
      SAUX2[tid] = mu; SAUX2[64 + tid] = lv;
      SAUX2[128 + tid] = mu + eps[tid] * expf(0.5f * lv);
    }
    __syncthreads();
    if (tid < 256) {
      float s = d1b[tid];
      for (int k = 0; k < 64; ++k) s += SAUX2[128 + k] * d1w[k * 256 + tid];
      gstore(&ws[OFF_D1 + tid], fmaxf(s, 0.f));
    } else if (tid == 256) {
      float s = 0.f;
      for (int t = 0; t < 64; ++t) {
        float mu = SAUX2[t], lv = SAUX2[64 + t];
        s += 1.f + lv - mu * mu - expf(lv);
      }
      gstore(&ws[OFF_KL], -0.5f * s / 64.f);
    }
  }
  gbar(flags, ++bt);

  // ================= Ph6: vec = d1@dec2 + b =================
  if (tid < 256) SAUX[tid] = gload(&ws[OFF_D1 + tid]);
  __syncthreads();
  {
    int c = bid * 146 + tid;
    if (tid < 146 && c < TRIN) {
      float s = d2b[c];
      #pragma unroll 4
      for (int k = 0; k < 256; ++k) s += SAUX[k] * d2w[k * TRIN + c];
      gstore(&ws[OFF_VEC + c], s);
    }
  }
  gbar(flags, ++bt);

  // ================= Ph7: B = sigmoid(sym logits); BD; rec partials =================
  for (int o = gtid; o < Nn * Nn; o += GT) {
    int a = o / Nn, b = o - (o / Nn) * Nn;
    int i = a < b ? a : b, j = a < b ? b : a;
    float l = gload(&ws[OFF_VEC + tri_idx(i, j)]);
    gstore(&ws[OFF_B + o], 1.f / (1.f + expf(-l)));
  }
  if (gtid < Nn) {
    int i = gtid, base = tri_idx(i, i);
    float s = 0.f;
    for (int j = i; j < Nn; ++j) {
      float v = gload(&ws[OFF_VEC + base + (j - i)]);
      float tt = A[i * Nn + j];
      s += fmaxf(v, 0.f) - v * tt + log1pf(expf(-fabsf(v)));
    }
    gstore(&ws[OFF_RECP + i], s);
  } else if (gtid < 2 * Nn) {
    int a = gtid - Nn;
    float l = gload(&ws[OFF_VEC + tri_idx(a, a)]);
    gstore(&ws[OFF_BD + a], 1.f / (1.f + expf(-l)));
  }
  gbar(flags, ++bt);

  // ================= Ph8: degB; Q; loss -> out[0] =================
  if (gtid < Nn) {
    int a = gtid; float s = 0.f;
    #pragma unroll 8
    for (int b = 0; b < Nn; ++b) s += gload(&ws[OFF_B + a * Nn + b]);
    gstore(&ws[OFF_DEGB + a], s);
  }
  for (int o = gtid; o < Nn * Nn; o += GT) {
    int a = o / Nn, b = o - (o / Nn) * Nn;
    float q = (a == b) ? 0.f
                       : gload(&ws[OFF_B + o]) * gload(&ws[OFF_BD + a]) * gload(&ws[OFF_BD + b]);
    gstore(&ws[OFF_Q + o], q);
  }
  if (gtid == GT - 1) {
    float s = 0.f;
    for (int i = 0; i < Nn; ++i) s += gload(&ws[OFF_RECP + i]);
    out[0] = s / (float)TRIN + gload(&ws[OFF_KL]);
  }
  gbar(flags, ++bt);

  // ================= MPM prep (block-local, no barrier) =================
  const int a0 = bid * 3;
  if (tid < 3 * Nn) Qsh[tid] = gload(&ws[OFF_Q + a0 * Nn + tid]);
  float Dreg = 0.f;
  if (tid < 3 * Nn) {
    int cl = tid / Nn, i = tid - cl * Nn;
    float bd = gload(&ws[OFF_BD + a0 + cl]);
    float db = gload(&ws[OFF_DEGB + a0 + cl]);
    Dreg = A[i * Nn + i] * bd / (fabsf(DEGAl[i] - db) + 1.f);
  }
  __syncthreads();

  // ================= MPM: 50 iterations, one fence-free barrier each =================
  float* Xcur = ws + OFF_X0;
  float* Xnew = ws + OFF_X1;

  for (int it = 0; it < NITER; ++it) {
    if (it == 0) {
      for (int o = tid; o < Nn * Nn; o += NT) {
        int a = o / Nn, i = o - a * Nn;
        SBIG[a * 97 + i] = 1.f / (float)Nn;     // ||u0|| = 1 exactly
      }
    } else {
      float pv = (tid < NB) ? gload(&ws[OFF_PART + tid]) : 0.f;
      if (tid < 64) {
        #pragma unroll
        for (int m = 16; m >= 1; m >>= 1) pv += __shfl_xor(pv, m, 64);
        if (tid == 0) sc[0] = sqrtf(pv);
      }
      for (int o2 = tid; o2 < (Nn * Nn) / 2; o2 += NT) {
        int a = o2 / 48, i0 = (o2 - a * 48) * 2;
        float fx, fy;
        gload2(Xcur + a * Nn + i0, fx, fy);
        SBIG[a * 97 + i0] = fx; SBIG[a * 97 + i0 + 1] = fy;
      }
    }
    __syncthreads();
    const float nrm = (it == 0) ? 1.f : sc[0];

    // M[j, a0+c] = max_b Q[a0+c, b] * X[j, b]
    if (tid < 4 * Nn) {
      int bseg = tid / Nn, j = tid - bseg * Nn;
      int b0 = bseg * 24;
      float m0 = 0.f, m1 = 0.f, m2 = 0.f;
      #pragma unroll
      for (int bb = 0; bb < 24; ++bb) {
        float xv = SBIG[(b0 + bb) * 97 + j];
        m0 = fmaxf(m0, Qsh[b0 + bb] * xv);
        m1 = fmaxf(m1, Qsh[Nn + b0 + bb] * xv);
        m2 = fmaxf(m2, Qsh[2 * Nn + b0 + bb] * xv);
      }
      partM[(bseg * 3 + 0) * Nn + j] = m0;
      partM[(bseg * 3 + 1) * Nn + j] = m1;
      partM[(bseg * 3 + 2) * Nn + j] = m2;
    }
    __syncthreads();
    if (tid < 3 * Nn) {
      int cl = tid / Nn, j = tid - cl * Nn;
      Msh[tid] = fmaxf(fmaxf(partM[cl * Nn + j], partM[(3 + cl) * Nn + j]),
                       fmaxf(partM[(6 + cl) * Nn + j], partM[(9 + cl) * Nn + j]));
    }
    __syncthreads();

    // msg (binary P via neighbor lists) + update + norm partial
    float val = 0.f;
    if (tid < 3 * Nn) {
      int cl = tid / Nn, i = tid - cl * Nn;
      float s = 0.f;
      int nc = ncnt[i];
      for (int k = 0; k < nc; ++k) s += Msh[cl * Nn + nbr[i * MAXD + k]];
      float xo = SBIG[(a0 + cl) * 97 + i];
      val = (xo * Dreg + s) / nrm;
      gstore(Xnew + (a0 + cl) * Nn + i, val);
    }
    float v2 = wsum64(val * val);
    if ((tid & 63) == 0) SAUX2[tid >> 6] = v2;
    __syncthreads();
    if (tid == 0) {
      float s = 0.f;
      #pragma unroll
      for (int w = 0; w < 8; ++w) s += SAUX2[w];
      gstore(&ws[OFF_PART + bid], s);
    }
    gbar(flags, ++bt);
    float* t = Xcur; Xcur = Xnew; Xnew = t;
  }

  // ================= final normalize + X output =================
  {
    float pv = (tid < NB) ? gload(&ws[OFF_PART + tid]) : 0.f;
    if (tid < 64) {
      #pragma unroll
      for (int m = 16; m >= 1; m >>= 1) pv += __shfl_xor(pv, m, 64);
      if (tid == 0) sc[1] = sqrtf(pv);
    }
    __syncthreads();
    float nrm = sc[1];
    for (int o = gtid; o < Nn * Nn; o += GT) {
      int i = o / Nn, a = o - (o / Nn) * Nn;
      out[1 + o] = gload(Xcur + a * Nn + i) / nrm;   // out[1 + i*96 + a] = X[i][a]
    }
  }
}

extern "C" void kernel_launch(void* const* d_in, const int* in_sizes, int n_in,
                              void* d_out, int out_size, void* d_ws, size_t ws_size,
                              hipStream_t stream) {
  const float* x   = (const float*)d_in[0];
  const int*   ei  = (const int*)d_in[1];
  const float* A   = (const float*)d_in[3];
  const float* w1  = (const float*)d_in[4];
  const float* b1  = (const float*)d_in[5];
  const float* g1  = (const float*)d_in[6];
  const float* be1 = (const float*)d_in[7];
  const float* w2  = (const float*)d_in[8];
  const float* b2  = (const float*)d_in[9];
  const float* g2  = (const float*)d_in[10];
  const float* be2 = (const float*)d_in[11];
  const float* muw = (const float*)d_in[12];
  const float* mub = (const float*)d_in[13];
  const float* lvw = (const float*)d_in[14];
  const float* lvb = (const float*)d_in[15];
  const float* d1w = (const float*)d_in[16];
  const float* d1b = (const float*)d_in[17];
  const float* d2w = (const float*)d_in[18];
  const float* d2b = (const float*)d_in[19];
  const float* eps = (const float*)d_in[20];
  float* ws  = (float*)d_ws;
  float* out = (float*)d_out;

  // zero only the 32 barrier flags
  hipMemsetAsync(ws, 0, NB * sizeof(int), stream);

  void* args[] = {
    (void*)&x, (void*)&ei, (void*)&A,
    (void*)&w1, (void*)&b1, (void*)&g1, (void*)&be1,
    (void*)&w2, (void*)&b2, (void*)&g2, (void*)&be2,
    (void*)&muw, (void*)&mub, (void*)&lvw, (void*)&lvb,
    (void*)&d1w, (void*)&d1b, (void*)&d2w, (void*)&d2b,
    (void*)&eps, (void*)&ws, (void*)&out
  };
  hipLaunchCooperativeKernel((void*)k_fused, dim3(NB), dim3(NT), args, 0, stream);
}

// Round 7
// 474.695 us; speedup vs baseline: 1.9398x; 1.2972x over previous
//
#include <hip/hip_runtime.h>
#include <cmath>

#define Nn 96
#define NB 32
#define NT 512
#define GT (NB*NT)
#define MAXD 40
#define NE 2048
#define TRIN 4656
#define NITER 50
#define SPIN_CAP (1 << 22)   // ~1000x margin over expected poll time; converts
                             // any protocol bug from "hang" into "wrong answer"
#define AGENT __HIP_MEMORY_SCOPE_AGENT

// workspace layout (floats); only FLAGS needs pre-zeroing
enum {
  OFF_FLAGS = 0,     // 32 ints (gbar)
  OFF_POOL  = 32,    // 256
  OFF_VEC   = 288,   // 4656
  OFF_XW    = 4944,  // 24576 (XW1 then XW2)
  OFF_H1    = 29520, // 24576
  OFF_X0    = 54096, // 9216  X triple buffer, Xg[a*96+i] = X[i][a]
  OFF_X1    = 63312, // 9216
  OFF_X2    = 72528, // 9216
  WS_END    = 81744
};

__device__ __forceinline__ int tri_idx(int i, int j) {  // i <= j
  return i * Nn - (i * (i - 1)) / 2 + (j - i);
}

// ---- MALL-coherent accessors: relaxed agent atomics (sc0+sc1, no fences) ----
__device__ __forceinline__ float gload(const float* p) {
  return __hip_atomic_load(p, __ATOMIC_RELAXED, AGENT);
}
__device__ __forceinline__ void gstore(float* p, float v) {
  __hip_atomic_store(p, v, __ATOMIC_RELAXED, AGENT);
}
__device__ __forceinline__ void gload2(const float* p, float& x, float& y) {
  unsigned long long u =
      __hip_atomic_load((const unsigned long long*)p, __ATOMIC_RELAXED, AGENT);
  union { unsigned long long u; float f[2]; } c; c.u = u;
  x = c.f[0]; y = c.f[1];
}

// fence-free grid barrier (prologue only): vmcnt drain + relaxed flag + poll
__device__ __forceinline__ void gbar(int* flags, int target) {
  asm volatile("s_waitcnt vmcnt(0)" ::: "memory");
  __syncthreads();
  if (threadIdx.x == 0)
    __hip_atomic_store(&flags[blockIdx.x], target, __ATOMIC_RELAXED, AGENT);
  if (threadIdx.x < NB)
    while (__hip_atomic_load(&flags[threadIdx.x], __ATOMIC_RELAXED, AGENT) < target) {}
  __syncthreads();
}

__device__ __forceinline__ float wsum64(float v) {
  #pragma unroll
  for (int m = 32; m >= 1; m >>= 1) v += __shfl_xor(v, m, 64);
  return v;
}

__global__ __launch_bounds__(NT)
void k_fused(const float* x, const int* ei, const float* A,
             const float* w1, const float* b1, const float* g1, const float* be1,
             const float* w2, const float* b2, const float* g2, const float* be2,
             const float* muw, const float* mub, const float* lvw, const float* lvb,
             const float* d1w, const float* d1b, const float* d2w, const float* d2b,
             const float* eps, float* ws, float* out) {
  __shared__ float SBIG[Nn * 97];   // AGG (stride 97) -> VEC stage -> XT
  __shared__ float SAUX[768];
  __shared__ float SAUX2[768];
  __shared__ float Qsh[3 * Nn];
  __shared__ float Msh[3 * Nn];
  __shared__ float partM[12 * Nn];
  __shared__ float red[NT];
  __shared__ float degl[Nn];
  __shared__ float DEGAl[Nn];
  __shared__ float Bdsh[Nn];
  __shared__ float DegBsh[4];
  __shared__ float mv[16];
  __shared__ float sc[4];
  __shared__ unsigned char nbr[Nn * MAXD];
  __shared__ int ncnt[Nn];

  const int tid  = threadIdx.x;
  const int bid  = blockIdx.x;
  const int gtid = bid * NT + tid;
  const int a0   = bid * 3;          // owned columns a0..a0+2
  int* flags = (int*)ws;
  int bt = 0;

  // ================= Ph1: local deg/AGG/degA/nbr (LDS) + XW = x@w1 =================
  for (int o = tid; o < Nn * 97; o += NT) SBIG[o] = 0.f;
  if (tid < Nn) degl[tid] = 0.f;
  __syncthreads();
  for (int e = tid; e < NE; e += NT) atomicAdd(&degl[ei[NE + e]], 1.f);
  if (tid < Nn) atomicAdd(&degl[tid], 1.f);
  __syncthreads();
  for (int e = tid; e < NE; e += NT) {
    int s = ei[e], d = ei[NE + e];
    float c = (1.f / sqrtf(degl[s])) * (1.f / sqrtf(degl[d]));
    atomicAdd(&SBIG[d * 97 + s], c);
  }
  if (tid < Nn) atomicAdd(&SBIG[tid * 97 + tid], 1.f / degl[tid]);
  if (tid < Nn) {
    float s = 0.f;
    for (int j = 0; j < Nn; ++j) s += A[tid * Nn + j];
    DEGAl[tid] = s;
    int cnt = 0;
    for (int j = 0; j < Nn; ++j)
      if (j != tid && A[tid * Nn + j] != 0.f && cnt < MAXD)
        nbr[tid * MAXD + cnt++] = (unsigned char)j;
    ncnt[tid] = cnt;
  }
  {
    if (tid < 192) SAUX[tid] = x[a0 * 64 + tid];   // 3 rows of x
    __syncthreads();
    for (int o = tid; o < 3 * 256; o += NT) {
      int rl = o >> 8, c = o & 255;
      float s = 0.f;
      #pragma unroll 8
      for (int k = 0; k < 64; ++k) s += SAUX[rl * 64 + k] * w1[k * 256 + c];
      gstore(&ws[OFF_XW + (a0 + rl) * 256 + c], s);
    }
  }
  gbar(flags, ++bt);

  // ================= Ph2: G = AGG@XW + b1 (8 cols/block) + bn1 -> H1 =================
  {
    const int c0 = bid * 8;
    for (int o = tid; o < 768; o += NT) {
      int cl = o / Nn, k = o - cl * Nn;
      SAUX[o] = gload(&ws[OFF_XW + k * 256 + c0 + cl]);
    }
    __syncthreads();
    for (int o = tid; o < 768; o += NT) {
      int cl = o / Nn, r = o - cl * Nn;
      float s = b1[c0 + cl];
      #pragma unroll 8
      for (int k = 0; k < Nn; ++k) s += SBIG[r * 97 + k] * SAUX[cl * Nn + k];
      SAUX2[cl * Nn + r] = s;
    }
    __syncthreads();
    if (tid < 8) {
      float m = 0.f;
      for (int r = 0; r < Nn; ++r) m += SAUX2[tid * Nn + r];
      m /= (float)Nn;
      float v = 0.f;
      for (int r = 0; r < Nn; ++r) { float d = SAUX2[tid * Nn + r] - m; v += d * d; }
      v /= (float)Nn;
      mv[tid * 2] = m; mv[tid * 2 + 1] = 1.f / sqrtf(v + 1e-5f);
    }
    __syncthreads();
    for (int o = tid; o < 768; o += NT) {
      int cl = o / Nn, r = o - cl * Nn; int c = c0 + cl;
      float y = (SAUX2[o] - mv[cl * 2]) * mv[cl * 2 + 1] * g1[c] + be1[c];
      gstore(&ws[OFF_H1 + r * 256 + c], fmaxf(y, 0.f));
    }
  }
  gbar(flags, ++bt);

  // ================= Ph3: XW2 = H1@w2 (3 rows/block) =================
  {
    for (int o = tid; o < 768; o += NT)
      SAUX[o] = gload(&ws[OFF_H1 + a0 * 256 + o]);
    __syncthreads();
    for (int o = tid; o < 768; o += NT) {
      int rl = o >> 8, c = o & 255;
      float s = 0.f;
      #pragma unroll 4
      for (int k = 0; k < 256; ++k) s += SAUX[rl * 256 + k] * w2[k * 256 + c];
      gstore(&ws[OFF_XW + (a0 + rl) * 256 + c], s);
    }
  }
  gbar(flags, ++bt);

  // ================= Ph4: G2 = AGG@XW2 + b2 (8 cols) + bn2 + pool =================
  {
    const int c0 = bid * 8;
    for (int o = tid; o < 768; o += NT) {
      int cl = o / Nn, k = o - cl * Nn;
      SAUX[o] = gload(&ws[OFF_XW + k * 256 + c0 + cl]);
    }
    __syncthreads();
    for (int o = tid; o < 768; o += NT) {
      int cl = o / Nn, r = o - cl * Nn;
      float s = b2[c0 + cl];
      #pragma unroll 8
      for (int k = 0; k < Nn; ++k) s += SBIG[r * 97 + k] * SAUX[cl * Nn + k];
      SAUX2[cl * Nn + r] = s;
    }
    __syncthreads();
    if (tid < 8) {
      int c = c0 + tid;
      float m = 0.f;
      for (int r = 0; r < Nn; ++r) m += SAUX2[tid * Nn + r];
      m /= (float)Nn;
      float v = 0.f;
      for (int r = 0; r < Nn; ++r) { float d = SAUX2[tid * Nn + r] - m; v += d * d; }
      v /= (float)Nn;
      float rs = 1.f / sqrtf(v + 1e-5f);
      float gg = g2[c], bb = be2[c], p = 0.f;
      for (int r = 0; r < Nn; ++r)
        p += fmaxf((SAUX2[tid * Nn + r] - m) * rs * gg + bb, 0.f);
      gstore(&ws[OFF_POOL + c], p);
    }
  }
  gbar(flags, ++bt);

  // ===== Ph5: X sentinels/init-prep + VAE head (redundant per block) + vec =====
  // sentinels: committed by this phase's trailing gbar -> no garbage-positive
  if (tid < 288) {
    gstore(&ws[OFF_X0 + a0 * 96 + tid], -1.f);
    gstore(&ws[OFF_X1 + a0 * 96 + tid], -1.f);
    gstore(&ws[OFF_X2 + a0 * 96 + tid], -1.f);
  }
  if (tid < 256) SAUX[tid] = gload(&ws[OFF_POOL + tid]);
  __syncthreads();
  if (tid < 64) {
    float mu = mub[tid], lv = lvb[tid];
    for (int k = 0; k < 256; ++k) {
      float g = SAUX[k];
      mu += g * muw[k * 64 + tid];
      lv += g * lvw[k * 64 + tid];
    }
    SAUX2[tid] = mu; SAUX2[64 + tid] = lv;
    SAUX2[128 + tid] = mu + eps[tid] * expf(0.5f * lv);
  }
  __syncthreads();
  if (tid < 256) {
    float s = d1b[tid];
    for (int k = 0; k < 64; ++k) s += SAUX2[128 + k] * d1w[k * 256 + tid];
    SAUX[256 + tid] = fmaxf(s, 0.f);            // d1 in LDS
  } else if (bid == 0 && tid == 256) {
    float s = 0.f;
    for (int t = 0; t < 64; ++t) {
      float mu = SAUX2[t], lv = SAUX2[64 + t];
      s += 1.f + lv - mu * mu - expf(lv);
    }
    sc[1] = -0.5f * s / 64.f;                   // KL (block 0 LDS)
  }
  __syncthreads();
  {
    int c = bid * 146 + tid;
    if (tid < 146 && c < TRIN) {
      float s = d2b[c];
      #pragma unroll 4
      for (int k = 0; k < 256; ++k) s += SAUX[256 + k] * d2w[k * TRIN + c];
      gstore(&ws[OFF_VEC + c], s);
    }
  }
  gbar(flags, ++bt);   // last grid barrier

  // ===== Ph6 (no barrier after): stage VEC; Q/D local; rec+KL -> out[0]; X2 init =====
  for (int o = tid; o < TRIN; o += NT) SBIG[o] = gload(&ws[OFF_VEC + o]);
  __syncthreads();
  if (tid < Nn) Bdsh[tid] = 1.f / (1.f + expf(-SBIG[tri_idx(tid, tid)]));
  __syncthreads();
  if (tid < 288) {
    int cl = tid / 96, b = tid - cl * 96, a = a0 + cl;
    int i_ = a < b ? a : b, j_ = a < b ? b : a;
    float s_ = 1.f / (1.f + expf(-SBIG[tri_idx(i_, j_)]));
    partM[cl * 96 + b] = s_;                      // for degB row sums
    Qsh[cl * 96 + b] = (a == b) ? 0.f : s_ * Bdsh[a] * Bdsh[b];
  }
  __syncthreads();
  if (tid < 3) {
    float s = 0.f;
    for (int b = 0; b < Nn; ++b) s += partM[tid * 96 + b];
    DegBsh[tid] = s;
  }
  __syncthreads();
  float Dreg = 0.f;
  if (tid < 288) {
    int cl = tid / 96, i = tid - cl * 96;
    Dreg = Bdsh[a0 + cl] / (fabsf(DEGAl[i] - DegBsh[cl]) + 1.f);  // A diag == 1
  }
  if (bid == 0) {
    float s = 0.f;
    for (int i = 0; i < Nn; ++i)
      for (int j = i + tid; j < Nn; j += NT) {
        float v = SBIG[tri_idx(i, j)];
        float tt = A[i * Nn + j];
        s += fmaxf(v, 0.f) - v * tt + log1pf(expf(-fabsf(v)));
      }
    red[tid] = s;
    __syncthreads();
    for (int st = 256; st >= 1; st >>= 1) { if (tid < st) red[tid] += red[tid + st]; __syncthreads(); }
    if (tid == 0) out[0] = red[0] / (float)TRIN + sc[1];
  }
  if (tid < 288) gstore(&ws[OFF_X2 + a0 * 96 + tid], 1.f / (float)Nn);  // ||x0||=1
  __syncthreads();

  // ================= MPM: 50 iterations, ZERO barriers (sign-sentinel sync) =======
  float* pr = ws + OFF_X2;   // read  (written t-1)
  float* ps = ws + OFF_X1;   // sentinel target (written t+1)
  float* pw = ws + OFF_X0;   // write (t)

  for (int it = 0; it < NITER; ++it) {
    // --- stage + per-element sign poll (bounded: deadlock -> wrong answer) ---
    float vx[9], vy[9]; int base[9];
    #pragma unroll
    for (int k = 0; k < 9; ++k) {
      int o2 = k * NT + tid;
      int a = o2 / 48, r = o2 - a * 48;
      base[k] = a * 96 + 2 * r;
      gload2(pr + base[k], vx[k], vy[k]);
    }
    #pragma unroll
    for (int k = 0; k < 9; ++k) {
      int guard = 0;
      while (fminf(vx[k], vy[k]) <= 0.f && ++guard < SPIN_CAP)
        gload2(pr + base[k], vx[k], vy[k]);
    }
    float ls = 0.f;
    #pragma unroll
    for (int k = 0; k < 9; ++k) {
      int o2 = k * NT + tid; int a = o2 / 48;
      int xi = base[k] + a;                      // a*97 + 2r
      SBIG[xi] = vx[k]; SBIG[xi + 1] = vy[k];
      ls += vx[k] * vx[k] + vy[k] * vy[k];
    }
    // sentinel own cols of the buffer this block rewrites NEXT iteration;
    // safe: pr fully present => all blocks finished reading ps last iter.
    if (tid < 288) gstore(ps + a0 * 96 + tid, -1.f);
    ls = wsum64(ls);
    if ((tid & 63) == 0) red[tid >> 6] = ls;
    __syncthreads();
    const float nrm = sqrtf(red[0] + red[1] + red[2] + red[3] +
                            red[4] + red[5] + red[6] + red[7]);   // identical all blocks

    // --- M[j, a0+c] = max_b Q[a0+c, b] * X[j, b] ---
    if (tid < 4 * Nn) {
      int bseg = tid / Nn, j = tid - bseg * Nn;
      int b0 = bseg * 24;
      float m0 = 0.f, m1 = 0.f, m2 = 0.f;
      #pragma unroll
      for (int bb = 0; bb < 24; ++bb) {
        float xv = SBIG[(b0 + bb) * 97 + j];
        m0 = fmaxf(m0, Qsh[b0 + bb] * xv);
        m1 = fmaxf(m1, Qsh[Nn + b0 + bb] * xv);
        m2 = fmaxf(m2, Qsh[2 * Nn + b0 + bb] * xv);
      }
      partM[(bseg * 3 + 0) * Nn + j] = m0;
      partM[(bseg * 3 + 1) * Nn + j] = m1;
      partM[(bseg * 3 + 2) * Nn + j] = m2;
    }
    __syncthreads();
    if (tid < 3 * Nn) {
      int cl = tid / Nn, j = tid - cl * Nn;
      Msh[tid] = fmaxf(fmaxf(partM[cl * Nn + j], partM[(3 + cl) * Nn + j]),
                       fmaxf(partM[(6 + cl) * Nn + j], partM[(9 + cl) * Nn + j]));
    }
    __syncthreads();

    // --- msg + update; clamp keeps strict positivity (poll protocol) ---
    float val = 0.f;
    if (tid < 288) {
      int cl = tid / 96, i = tid - cl * 96;
      float s = 0.f;
      int nc = ncnt[i];
      for (int k = 0; k < nc; ++k) s += Msh[cl * Nn + nbr[i * MAXD + k]];
      float xo = SBIG[(a0 + cl) * 97 + i];
      val = fmaxf((xo * Dreg + s) / nrm, 1e-30f);
    }
    // drain sentinel stores before data stores (same wave => MALL order per slot)
    asm volatile("s_waitcnt vmcnt(0)" ::: "memory");
    if (tid < 288) gstore(pw + a0 * 96 + tid, val);
    __syncthreads();   // protect SBIG/partM/red reuse next iteration
    float* t_ = pr; pr = pw; pw = ps; ps = t_;   // (rd,snt,wr) <- (wr,rd,snt)
  }

  // ================= final: block 0 stages X[1], normalizes, writes out =========
  if (bid != 0) return;
  {
    float vx[9], vy[9]; int base[9];
    #pragma unroll
    for (int k = 0; k < 9; ++k) {
      int o2 = k * NT + tid;
      int a = o2 / 48, r = o2 - a * 48;
      base[k] = a * 96 + 2 * r;
      gload2(pr + base[k], vx[k], vy[k]);
    }
    #pragma unroll
    for (int k = 0; k < 9; ++k) {
      int guard = 0;
      while (fminf(vx[k], vy[k]) <= 0.f && ++guard < SPIN_CAP)
        gload2(pr + base[k], vx[k], vy[k]);
    }
    float ls = 0.f;
    #pragma unroll
    for (int k = 0; k < 9; ++k) ls += vx[k] * vx[k] + vy[k] * vy[k];
    ls = wsum64(ls);
    if ((tid & 63) == 0) red[tid >> 6] = ls;
    __syncthreads();
    const float nrm = sqrtf(red[0] + red[1] + red[2] + red[3] +
                            red[4] + red[5] + red[6] + red[7]);
    #pragma unroll
    for (int k = 0; k < 9; ++k) {
      int o2 = k * NT + tid;
      int a = o2 / 48, i0 = 2 * (o2 - a * 48);
      out[1 + i0 * 96 + a] = vx[k] / nrm;        // out[1 + i*96 + a] = X[i][a]
      out[1 + (i0 + 1) * 96 + a] = vy[k] / nrm;
    }
  }
}

extern "C" void kernel_launch(void* const* d_in, const int* in_sizes, int n_in,
                              void* d_out, int out_size, void* d_ws, size_t ws_size,
                              hipStream_t stream) {
  const float* x   = (const float*)d_in[0];
  const int*   ei  = (const int*)d_in[1];
  const float* A   = (const float*)d_in[3];
  const float* w1  = (const float*)d_in[4];
  const float* b1  = (const float*)d_in[5];
  const float* g1  = (const float*)d_in[6];
  const float* be1 = (const float*)d_in[7];
  const float* w2  = (const float*)d_in[8];
  const float* b2  = (const float*)d_in[9];
  const float* g2  = (const float*)d_in[10];
  const float* be2 = (const float*)d_in[11];
  const float* muw = (const float*)d_in[12];
  const float* mub = (const float*)d_in[13];
  const float* lvw = (const float*)d_in[14];
  const float* lvb = (const float*)d_in[15];
  const float* d1w = (const float*)d_in[16];
  const float* d1b = (const float*)d_in[17];
  const float* d2w = (const float*)d_in[18];
  const float* d2b = (const float*)d_in[19];
  const float* eps = (const float*)d_in[20];
  float* ws  = (float*)d_ws;
  float* out = (float*)d_out;

  // zero only the 32 barrier flags
  hipMemsetAsync(ws, 0, NB * sizeof(int), stream);

  // plain launch: 32 blocks always co-resident on 256 CUs; spin barriers +
  // sign-sentinel MPM need co-residency only, not the cooperative API.
  k_fused<<<dim3(NB), dim3(NT), 0, stream>>>(
      x, ei, A, w1, b1, g1, be1, w2, b2, g2, be2,
      muw, mub, lvw, lvb, d1w, d1b, d2w, d2b, eps, ws, out);
}

// Round 10
// 472.542 us; speedup vs baseline: 1.9486x; 1.0046x over previous
//
#include <hip/hip_runtime.h>
#include <cmath>

#define Nn 96
#define NB 32
#define NT 512
#define MAXD 40
#define NE 2048
#define TRIN 4656
#define NITER 50
#define SPIN_CAP (1 << 20)   // retry ROUNDS (each ~1 RT); converts bug->wrong answer
#define AGENT __HIP_MEMORY_SCOPE_AGENT

// workspace layout (floats); only FLAGS needs pre-zeroing
enum {
  OFF_FLAGS = 0,     // 32 ints (gbar)
  OFF_POOL  = 32,    // 256
  OFF_VEC   = 288,   // 4656
  OFF_XW    = 4944,  // 24576 (XW2 exchange)
  OFF_H1    = 29520, // 24576
  OFF_X0    = 54096, // 9216  X triple buffer, Xg[a*96+i] = X[i][a]
  OFF_X1    = 63312, // 9216
  OFF_X2    = 72528, // 9216
  WS_END    = 81744
};

__device__ __forceinline__ int tri_idx(int i, int j) {  // i <= j
  return i * Nn - (i * (i - 1)) / 2 + (j - i);
}

// ---- MALL-coherent accessors: relaxed agent atomics (sc0+sc1, no fences) ----
__device__ __forceinline__ float gload(const float* p) {
  return __hip_atomic_load(p, __ATOMIC_RELAXED, AGENT);
}
__device__ __forceinline__ void gstore(float* p, float v) {
  __hip_atomic_store(p, v, __ATOMIC_RELAXED, AGENT);
}
__device__ __forceinline__ void gload2(const float* p, float& x, float& y) {
  unsigned long long u =
      __hip_atomic_load((const unsigned long long*)p, __ATOMIC_RELAXED, AGENT);
  union { unsigned long long u; float f[2]; } c; c.u = u;
  x = c.f[0]; y = c.f[1];
}
__device__ __forceinline__ void gstore2(float* p, float a, float b) {
  union { unsigned long long u; float f[2]; } c; c.f[0] = a; c.f[1] = b;
  __hip_atomic_store((unsigned long long*)p, c.u, __ATOMIC_RELAXED, AGENT);
}

// fence-free grid barrier (prologue only): vmcnt drain + relaxed flag + poll
__device__ __forceinline__ void gbar(int* flags, int target) {
  asm volatile("s_waitcnt vmcnt(0)" ::: "memory");
  __syncthreads();
  if (threadIdx.x == 0)
    __hip_atomic_store(&flags[blockIdx.x], target, __ATOMIC_RELAXED, AGENT);
  if (threadIdx.x < NB)
    while (__hip_atomic_load(&flags[threadIdx.x], __ATOMIC_RELAXED, AGENT) < target) {}
  __syncthreads();
}

__device__ __forceinline__ float wsum64(float v) {
  #pragma unroll
  for (int m = 32; m >= 1; m >>= 1) v += __shfl_xor(v, m, 64);
  return v;
}

__global__ __launch_bounds__(NT)
void k_fused(const float* x, const int* ei, const float* A,
             const float* w1, const float* b1, const float* g1, const float* be1,
             const float* w2, const float* b2, const float* g2, const float* be2,
             const float* muw, const float* mub, const float* lvw, const float* lvb,
             const float* d1w, const float* d1b, const float* d2w, const float* d2b,
             const float* eps, float* ws, float* out) {
  __shared__ float SBIG[Nn * 97];   // AGG (stride 97) -> VEC stage -> XT
  __shared__ float SAUX[768];
  __shared__ float SAUX2[768];
  __shared__ float Qsh[3 * Nn];
  __shared__ float Msh[3 * Nn];
  __shared__ float partM[12 * Nn];
  __shared__ float red[NT];
  __shared__ float degl[Nn];
  __shared__ float DEGAl[Nn];
  __shared__ float Bdsh[Nn];
  __shared__ float DegBsh[4];
  __shared__ float sc[4];
  __shared__ unsigned char nbr[Nn * MAXD];
  __shared__ int ncnt[Nn];

  const int tid = threadIdx.x;
  const int bid = blockIdx.x;
  const int a0  = bid * 3;   // owned X columns / H1 rows
  const int c0  = bid * 8;   // owned feature columns
  int* flags = (int*)ws;
  int bt = 0;

  // ============ Ph1: deg/AGG/degA/nbr (LDS) + local XW(8 cols) + G + bn1 -> H1 ====
  for (int o = tid; o < Nn * 97; o += NT) SBIG[o] = 0.f;
  if (tid < Nn) degl[tid] = 0.f;
  __syncthreads();
  for (int e = tid; e < NE; e += NT) atomicAdd(&degl[ei[NE + e]], 1.f);
  if (tid < Nn) atomicAdd(&degl[tid], 1.f);
  __syncthreads();
  for (int e = tid; e < NE; e += NT) {
    int s = ei[e], d = ei[NE + e];
    float c = (1.f / sqrtf(degl[s])) * (1.f / sqrtf(degl[d]));
    atomicAdd(&SBIG[d * 97 + s], c);
  }
  if (tid < Nn) atomicAdd(&SBIG[tid * 97 + tid], 1.f / degl[tid]);
  if (tid < Nn) {
    float s = 0.f;
    for (int j = 0; j < Nn; ++j) s += A[tid * Nn + j];
    DEGAl[tid] = s;
    int cnt = 0;
    for (int j = 0; j < Nn; ++j)
      if (j != tid && A[tid * Nn + j] != 0.f && cnt < MAXD)
        nbr[tid * MAXD + cnt++] = (unsigned char)j;
    ncnt[tid] = cnt;
  }
  // XW for own 8 cols only (no exchange): SAUX[cl*96+k] = (x @ w1)[k][c0+cl]
  for (int o = tid; o < 768; o += NT) {
    int cl = o / Nn, k = o - cl * Nn;
    float s = 0.f;
    #pragma unroll 8
    for (int kk = 0; kk < 64; ++kk) s += x[k * 64 + kk] * w1[kk * 256 + c0 + cl];
    SAUX[o] = s;
  }
  __syncthreads();
  for (int o = tid; o < 768; o += NT) {
    int cl = o / Nn, r = o - cl * Nn;
    float s = b1[c0 + cl];
    #pragma unroll 8
    for (int k = 0; k < Nn; ++k) s += SBIG[r * 97 + k] * SAUX[cl * Nn + k];
    SAUX2[cl * Nn + r] = s;
  }
  __syncthreads();
  if (tid < 8) {
    int c = c0 + tid;
    float m = 0.f;
    for (int r = 0; r < Nn; ++r) m += SAUX2[tid * Nn + r];
    m /= (float)Nn;
    float v = 0.f;
    for (int r = 0; r < Nn; ++r) { float d = SAUX2[tid * Nn + r] - m; v += d * d; }
    v /= (float)Nn;
    float rs = 1.f / sqrtf(v + 1e-5f);
    float gg = g1[c], bb = be1[c];
    for (int r = 0; r < Nn; ++r) {
      float y = (SAUX2[tid * Nn + r] - m) * rs * gg + bb;
      gstore(&ws[OFF_H1 + r * 256 + c], fmaxf(y, 0.f));
    }
  }
  gbar(flags, ++bt);

  // ================= Ph2: XW2 = H1@w2 (3 rows/block) =================
  {
    for (int o = tid; o < 768; o += NT)
      SAUX[o] = gload(&ws[OFF_H1 + a0 * 256 + o]);
    __syncthreads();
    for (int o = tid; o < 768; o += NT) {
      int rl = o >> 8, c = o & 255;
      float s = 0.f;
      #pragma unroll 4
      for (int k = 0; k < 256; ++k) s += SAUX[rl * 256 + k] * w2[k * 256 + c];
      gstore(&ws[OFF_XW + (a0 + rl) * 256 + c], s);
    }
  }
  gbar(flags, ++bt);

  // ================= Ph3: G2 = AGG@XW2 + b2 (8 cols) + bn2 + pool =================
  {
    for (int o = tid; o < 768; o += NT) {
      int cl = o / Nn, k = o - cl * Nn;
      SAUX[o] = gload(&ws[OFF_XW + k * 256 + c0 + cl]);
    }
    __syncthreads();
    for (int o = tid; o < 768; o += NT) {
      int cl = o / Nn, r = o - cl * Nn;
      float s = b2[c0 + cl];
      #pragma unroll 8
      for (int k = 0; k < Nn; ++k) s += SBIG[r * 97 + k] * SAUX[cl * Nn + k];
      SAUX2[cl * Nn + r] = s;
    }
    __syncthreads();
    if (tid < 8) {
      int c = c0 + tid;
      float m = 0.f;
      for (int r = 0; r < Nn; ++r) m += SAUX2[tid * Nn + r];
      m /= (float)Nn;
      float v = 0.f;
      for (int r = 0; r < Nn; ++r) { float d = SAUX2[tid * Nn + r] - m; v += d * d; }
      v /= (float)Nn;
      float rs = 1.f / sqrtf(v + 1e-5f);
      float gg = g2[c], bb = be2[c], p = 0.f;
      for (int r = 0; r < Nn; ++r)
        p += fmaxf((SAUX2[tid * Nn + r] - m) * rs * gg + bb, 0.f);
      gstore(&ws[OFF_POOL + c], p);
    }
  }
  gbar(flags, ++bt);

  // ===== Ph4: X sentinels + VAE head (redundant per block) + vec(146 cols) =====
  if (tid < 288 && !(tid & 1)) {
    gstore2(&ws[OFF_X0 + a0 * 96 + tid], -1.f, -1.f);
    gstore2(&ws[OFF_X1 + a0 * 96 + tid], -1.f, -1.f);
    gstore2(&ws[OFF_X2 + a0 * 96 + tid], -1.f, -1.f);
  }
  if (tid < 256) SAUX[tid] = gload(&ws[OFF_POOL + tid]);
  __syncthreads();
  if (tid < 64) {
    float mu = mub[tid], lv = lvb[tid];
    for (int k = 0; k < 256; ++k) {
      float g = SAUX[k];
      mu += g * muw[k * 64 + tid];
      lv += g * lvw[k * 64 + tid];
    }
    SAUX2[tid] = mu; SAUX2[64 + tid] = lv;
    SAUX2[128 + tid] = mu + eps[tid] * expf(0.5f * lv);
  }
  __syncthreads();
  if (tid < 256) {
    float s = d1b[tid];
    for (int k = 0; k < 64; ++k) s += SAUX2[128 + k] * d1w[k * 256 + tid];
    SAUX[256 + tid] = fmaxf(s, 0.f);            // d1 in LDS
  } else if (bid == 0 && tid == 256) {
    float s = 0.f;
    for (int t = 0; t < 64; ++t) {
      float mu = SAUX2[t], lv = SAUX2[64 + t];
      s += 1.f + lv - mu * mu - expf(lv);
    }
    sc[1] = -0.5f * s / 64.f;                   // KL (block 0 LDS)
  }
  __syncthreads();
  {
    int c = bid * 146 + tid;
    if (tid < 146 && c < TRIN) {
      float s = d2b[c];
      #pragma unroll 4
      for (int k = 0; k < 256; ++k) s += SAUX[256 + k] * d2w[k * TRIN + c];
      gstore(&ws[OFF_VEC + c], s);
    }
  }
  gbar(flags, ++bt);   // last grid barrier

  // ===== Ph5 (no barrier after): stage VEC; Q/D local; rec+KL -> out[0]; X2 init ===
  for (int o = tid; o < TRIN; o += NT) SBIG[o] = gload(&ws[OFF_VEC + o]);
  __syncthreads();
  if (tid < Nn) Bdsh[tid] = 1.f / (1.f + expf(-SBIG[tri_idx(tid, tid)]));
  __syncthreads();
  if (tid < 288) {
    int cl = tid / 96, b = tid - cl * 96, a = a0 + cl;
    int i_ = a < b ? a : b, j_ = a < b ? b : a;
    float s_ = 1.f / (1.f + expf(-SBIG[tri_idx(i_, j_)]));
    partM[cl * 96 + b] = s_;                      // for degB row sums
    Qsh[cl * 96 + b] = (a == b) ? 0.f : s_ * Bdsh[a] * Bdsh[b];
  }
  __syncthreads();
  if (tid < 3) {
    float s = 0.f;
    for (int b = 0; b < Nn; ++b) s += partM[tid * 96 + b];
    DegBsh[tid] = s;
  }
  __syncthreads();
  float Dreg = 0.f;
  if (tid < 288) {
    int cl = tid / 96, i = tid - cl * 96;
    Dreg = Bdsh[a0 + cl] / (fabsf(DEGAl[i] - DegBsh[cl]) + 1.f);  // A diag == 1
  }
  if (bid == 0) {
    float s = 0.f;
    for (int i = 0; i < Nn; ++i)
      for (int j = i + tid; j < Nn; j += NT) {
        float v = SBIG[tri_idx(i, j)];
        float tt = A[i * Nn + j];
        s += fmaxf(v, 0.f) - v * tt + log1pf(expf(-fabsf(v)));
      }
    red[tid] = s;
    __syncthreads();
    for (int st = 256; st >= 1; st >>= 1) { if (tid < st) red[tid] += red[tid + st]; __syncthreads(); }
    if (tid == 0) out[0] = red[0] / (float)TRIN + sc[1];
  }
  if (tid < 288 && !(tid & 1))
    gstore2(&ws[OFF_X2 + a0 * 96 + tid], 1.f / (float)Nn, 1.f / (float)Nn);  // ||x0||=1
  __syncthreads();

  // ================= MPM: 50 iterations, ZERO barriers (sign-sentinel sync) =======
  float* pr = ws + OFF_X2;   // read  (written t-1)
  float* ps = ws + OFF_X1;   // sentinel target (becomes write buffer at t+1)
  float* pw = ws + OFF_X0;   // write (t)

  for (int it = 0; it < NITER; ++it) {
    // --- stage + PARALLEL-retry sign poll: re-issue only stale slots per round ---
    float vx[9], vy[9]; int base[9];
    #pragma unroll
    for (int k = 0; k < 9; ++k) {
      int o2 = k * NT + tid;
      int a = o2 / 48, r = o2 - a * 48;
      base[k] = a * 96 + 2 * r;
      gload2(pr + base[k], vx[k], vy[k]);
    }
    for (int guard = 0; guard < SPIN_CAP; ++guard) {
      float mn = 1e30f;
      #pragma unroll
      for (int k = 0; k < 9; ++k) mn = fminf(mn, fminf(vx[k], vy[k]));
      if (mn > 0.f) break;
      #pragma unroll
      for (int k = 0; k < 9; ++k)
        if (fminf(vx[k], vy[k]) <= 0.f) gload2(pr + base[k], vx[k], vy[k]);
    }
    float ls = 0.f;
    #pragma unroll
    for (int k = 0; k < 9; ++k) {
      int o2 = k * NT + tid; int a = o2 / 48;
      int xi = base[k] + a;                      // a*97 + 2r
      SBIG[xi] = vx[k]; SBIG[xi + 1] = vy[k];
      ls += vx[k] * vx[k] + vy[k] * vy[k];
    }
    // sentinel own cols of the buffer this block rewrites NEXT iteration;
    // safe: pr fully present => all blocks finished reading ps last iter.
    if (tid < 288 && !(tid & 1)) gstore2(ps + a0 * 96 + tid, -1.f, -1.f);
    ls = wsum64(ls);
    if ((tid & 63) == 0) red[tid >> 6] = ls;
    __syncthreads();
    const float nrm = sqrtf(red[0] + red[1] + red[2] + red[3] +
                            red[4] + red[5] + red[6] + red[7]);   // identical all blocks

    // --- M[j, a0+c] = max_b Q[a0+c, b] * X[j, b] ---
    if (tid < 4 * Nn) {
      int bseg = tid / Nn, j = tid - bseg * Nn;
      int b0 = bseg * 24;
      float m0 = 0.f, m1 = 0.f, m2 = 0.f;
      #pragma unroll
      for (int bb = 0; bb < 24; ++bb) {
        float xv = SBIG[(b0 + bb) * 97 + j];
        m0 = fmaxf(m0, Qsh[b0 + bb] * xv);
        m1 = fmaxf(m1, Qsh[Nn + b0 + bb] * xv);
        m2 = fmaxf(m2, Qsh[2 * Nn + b0 + bb] * xv);
      }
      partM[(bseg * 3 + 0) * Nn + j] = m0;
      partM[(bseg * 3 + 1) * Nn + j] = m1;
      partM[(bseg * 3 + 2) * Nn + j] = m2;
    }
    __syncthreads();
    if (tid < 3 * Nn) {
      int cl = tid / Nn, j = tid - cl * Nn;
      Msh[tid] = fmaxf(fmaxf(partM[cl * Nn + j], partM[(3 + cl) * Nn + j]),
                       fmaxf(partM[(6 + cl) * Nn + j], partM[(9 + cl) * Nn + j]));
    }
    __syncthreads();

    // --- msg + update; clamp keeps strict positivity (poll protocol) ---
    float val = 0.f;
    if (tid < 288) {
      int cl = tid / 96, i = tid - cl * 96;
      float s = 0.f;
      int nc = ncnt[i];
      for (int k = 0; k < nc; ++k) s += Msh[cl * Nn + nbr[i * MAXD + k]];
      float xo = SBIG[(a0 + cl) * 97 + i];
      val = fmaxf((xo * Dreg + s) / nrm, 1e-30f);
    }
    float pvv = __shfl_xor(val, 1, 64);   // partner (odd-lane) value
    // drain sentinel stores before data stores (same block, same addrs at t+1)
    asm volatile("s_waitcnt vmcnt(0)" ::: "memory");
    if (tid < 288 && !(tid & 1)) gstore2(pw + a0 * 96 + tid, val, pvv);
    __syncthreads();   // protect SBIG/partM/red reuse next iteration
    float* t_ = pr; pr = pw; pw = ps; ps = t_;   // (rd,snt,wr) <- (wr,rd,snt)
  }

  // ================= final: block 0 stages X(49), normalizes, writes out =========
  if (bid != 0) return;
  {
    float vx[9], vy[9]; int base[9];
    #pragma unroll
    for (int k = 0; k < 9; ++k) {
      int o2 = k * NT + tid;
      int a = o2 / 48, r = o2 - a * 48;
      base[k] = a * 96 + 2 * r;
      gload2(pr + base[k], vx[k], vy[k]);
    }
    for (int guard = 0; guard < SPIN_CAP; ++guard) {
      float mn = 1e30f;
      #pragma unroll
      for (int k = 0; k < 9; ++k) mn = fminf(mn, fminf(vx[k], vy[k]));
      if (mn > 0.f) break;
      #pragma unroll
      for (int k = 0; k < 9; ++k)
        if (fminf(vx[k], vy[k]) <= 0.f) gload2(pr + base[k], vx[k], vy[k]);
    }
    float ls = 0.f;
    #pragma unroll
    for (int k = 0; k < 9; ++k) ls += vx[k] * vx[k] + vy[k] * vy[k];
    ls = wsum64(ls);
    if ((tid & 63) == 0) red[tid >> 6] = ls;
    __syncthreads();
    const float nrm = sqrtf(red[0] + red[1] + red[2] + red[3] +
                            red[4] + red[5] + red[6] + red[7]);
    #pragma unroll
    for (int k = 0; k < 9; ++k) {
      int o2 = k * NT + tid;
      int a = o2 / 48, i0 = 2 * (o2 - a * 48);
      out[1 + i0 * 96 + a] = vx[k] / nrm;        // out[1 + i*96 + a] = X[i][a]
      out[1 + (i0 + 1) * 96 + a] = vy[k] / nrm;
    }
  }
}

extern "C" void kernel_launch(void* const* d_in, const int* in_sizes, int n_in,
                              void* d_out, int out_size, void* d_ws, size_t ws_size,
                              hipStream_t stream) {
  const float* x   = (const float*)d_in[0];
  const int*   ei  = (const int*)d_in[1];
  const float* A   = (const float*)d_in[3];
  const float* w1  = (const float*)d_in[4];
  const float* b1  = (const float*)d_in[5];
  const float* g1  = (const float*)d_in[6];
  const float* be1 = (const float*)d_in[7];
  const float* w2  = (const float*)d_in[8];
  const float* b2  = (const float*)d_in[9];
  const float* g2  = (const float*)d_in[10];
  const float* be2 = (const float*)d_in[11];
  const float* muw = (const float*)d_in[12];
  const float* mub = (const float*)d_in[13];
  const float* lvw = (const float*)d_in[14];
  const float* lvb = (const float*)d_in[15];
  const float* d1w = (const float*)d_in[16];
  const float* d1b = (const float*)d_in[17];
  const float* d2w = (const float*)d_in[18];
  const float* d2b = (const float*)d_in[19];
  const float* eps = (const float*)d_in[20];
  float* ws  = (float*)d_ws;
  float* out = (float*)d_out;

  // zero only the 32 barrier flags
  hipMemsetAsync(ws, 0, NB * sizeof(int), stream);

  // plain launch: 32 blocks always co-resident on 256 CUs; spin barriers +
  // sign-sentinel MPM need co-residency only, not the cooperative API.
  k_fused<<<dim3(NB), dim3(NT), 0, stream>>>(
      x, ei, A, w1, b1, g1, be1, w2, b2, g2, be2,
      muw, mub, lvw, lvb, d1w, d1b, d2w, d2b, eps, ws, out);
}